// Round 16
// baseline (366.618 us; speedup 1.0000x reference)
//
#include <hip/hip_runtime.h>
#include <hip/hip_fp16.h>
#include <math.h>

#define NN 100000
#define DD 128
#define AGG_BLOCKS 2048

#define NBUCK 196         // ceil(NN / 512)
#define BSH 9             // bucket width 512 nodes
#define BW 512
#define CAP 10240         // per-bucket capacity (mean 8163, sigma ~90)
#define APASS 392         // bucket_scatter blocks
#define FILLB (NBUCK * 4) // 784 fill blocks
#define CURPAD 32         // ints between cursors (one 128B line each)

typedef short short8 __attribute__((ext_vector_type(8)));
typedef _Float16 half8 __attribute__((ext_vector_type(8)));
typedef float f32x4 __attribute__((ext_vector_type(4)));

// ---------------- bucket pass A: count + scatter packed edges ----------------
// packed[b*CAP + r] = (d_local << 17) | src   (d_local<512, src<131072)
__global__ __launch_bounds__(256) void bucket_scatter_kernel(
    const int* __restrict__ src, const int* __restrict__ dst, int E,
    int* __restrict__ cur, int* __restrict__ packed)
{
    __shared__ int h[NBUCK];
    __shared__ int base[NBUCK];
    __shared__ int c2[NBUCK];

    const int tid = threadIdx.x;
    const int chunk = (E + APASS - 1) / APASS;
    const int e0 = blockIdx.x * chunk;
    const int e1 = min(e0 + chunk, E);

    if (tid < NBUCK) { h[tid] = 0; c2[tid] = 0; }
    __syncthreads();

    for (int e = e0 + tid; e < e1; e += 256)
        atomicAdd(&h[dst[e] >> BSH], 1);
    __syncthreads();

    if (tid < NBUCK && h[tid] > 0)
        base[tid] = atomicAdd(&cur[tid * CURPAD], h[tid]);
    __syncthreads();

    for (int e = e0 + tid; e < e1; e += 256) {
        int d = dst[e];
        int b = d >> BSH;
        int r = atomicAdd(&c2[b], 1);
        int pos = base[b] + r;
        if (pos < CAP)
            packed[b * CAP + pos] = ((d & (BW - 1)) << 17) | src[e];
    }
}

// ---------------- bucket pass B: per-bucket count + offsets + dinv + cursor ----------------
// one block per bucket; absorbs the cross-bucket scan (each block prefixes cur[]).
__global__ __launch_bounds__(256) void bucket_count_kernel(
    const int* __restrict__ cur, const int* __restrict__ packed,
    int* __restrict__ offsets, int* __restrict__ cursor,
    float* __restrict__ dinv)
{
    __shared__ int cnt[BW];
    __shared__ int ts[256];
    __shared__ int cbase_sh;

    const int tid = threadIdx.x;
    const int b = blockIdx.x;

    cnt[tid] = 0;
    cnt[tid + 256] = 0;
    __syncthreads();

    int c = cur[b * CURPAD];
    if (c > CAP) c = CAP;
    const int pbase = b * CAP;
    for (int i = tid; i < c; i += 256)
        atomicAdd(&cnt[packed[pbase + i] >> 17], 1);

    // cross-bucket prefix: scan clamped cur[] over 196 buckets
    int myc = 0;
    if (tid < NBUCK) {
        myc = cur[tid * CURPAD];
        if (myc > CAP) myc = CAP;
    }
    ts[tid] = myc;
    __syncthreads();          // count atomics done + ts ready
    for (int d = 1; d < 256; d <<= 1) {
        int t = (tid >= d) ? ts[tid - d] : 0;
        __syncthreads();
        ts[tid] += t;
        __syncthreads();
    }
    if (tid == 0) cbase_sh = (b > 0) ? ts[b - 1] : 0;
    if (b == 0 && tid == 0) offsets[NN] = ts[NBUCK - 1];
    __syncthreads();
    const int cb = cbase_sh;

    // within-bucket prefix over 512 node counts (2 per thread)
    int v0 = cnt[tid * 2];
    int v1 = cnt[tid * 2 + 1];
    int s = v0 + v1;
    __syncthreads();          // ts reuse
    ts[tid] = s;
    __syncthreads();
    for (int d = 1; d < 256; d <<= 1) {
        int t = (tid >= d) ? ts[tid - d] : 0;
        __syncthreads();
        ts[tid] += t;
        __syncthreads();
    }
    int ex = ts[tid] - s;

    int node0 = (b << BSH) + tid * 2;
    if (node0 < NN) {
        int o0 = cb + ex;
        offsets[node0] = o0;
        cursor[node0] = o0;
        dinv[node0] = rsqrtf((float)v0 + 1.0f);
    }
    int node1 = node0 + 1;
    if (node1 < NN) {
        int o1 = cb + ex + v0;
        offsets[node1] = o1;
        cursor[node1] = o1;
        dinv[node1] = rsqrtf((float)v1 + 1.0f);
    }
}

// ---------------- bucket pass C: parallel CSR fill (4 blocks per bucket) ----------------
__global__ __launch_bounds__(256) void bucket_fill_kernel(
    const int* __restrict__ cur, const int* __restrict__ packed,
    int* __restrict__ cursor, int* __restrict__ csr)
{
    const int tid = threadIdx.x;
    const int b = blockIdx.x >> 2;
    const int q = blockIdx.x & 3;

    int c = cur[b * CURPAD];
    if (c > CAP) c = CAP;
    const int qs = (c + 3) >> 2;
    const int i0 = q * qs;
    const int i1 = min(i0 + qs, c);
    const int pbase = b * CAP;

    for (int i = i0 + tid; i < i1; i += 256) {
        int p = packed[pbase + i];
        int node = (b << BSH) + (p >> 17);
        int pos = atomicAdd(&cursor[node], 1);
        csr[pos] = p & 0x1FFFF;
    }
}

// ---------------- helpers: fp32 -> bf16 / fp16 splits ----------------
__device__ __forceinline__ unsigned short f2bf(float f) {
    unsigned int u = __float_as_uint(f);
    unsigned int r = u + 0x7FFFu + ((u >> 16) & 1u);
    return (unsigned short)(r >> 16);
}

__device__ __forceinline__ void split8(const float* v, short8& hi, short8& lo) {
    #pragma unroll
    for (int j = 0; j < 8; ++j) {
        float f = v[j];
        unsigned short h = f2bf(f);
        float fl = f - __uint_as_float(((unsigned int)h) << 16);
        hi[j] = (short)h;
        lo[j] = (short)f2bf(fl);
    }
}

// fp16 2-term split: W = hi + lo with fp32-compensated residual
__device__ __forceinline__ void split8h(const float* v, half8& hi, half8& lo) {
    #pragma unroll
    for (int j = 0; j < 8; ++j) {
        _Float16 h = (_Float16)v[j];
        float fl = v[j] - (float)h;
        hi[j] = h;
        lo[j] = (_Float16)fl;
    }
}

// truncating bf16 split (exactly compensated); packs via v_perm.
__device__ __forceinline__ void split8t(const float* v, short8& hi, short8& lo) {
    const unsigned int* u = (const unsigned int*)v;
    float lof[8];
    #pragma unroll
    for (int j = 0; j < 8; ++j)
        lof[j] = v[j] - __uint_as_float(u[j] & 0xFFFF0000u);
    const unsigned int* lu = (const unsigned int*)lof;
    union { short8 s; unsigned int w[4]; } H, L;
    #pragma unroll
    for (int q = 0; q < 4; ++q) {
#if __has_builtin(__builtin_amdgcn_perm)
        H.w[q] = __builtin_amdgcn_perm(u[2 * q + 1], u[2 * q], 0x07060302u);
        L.w[q] = __builtin_amdgcn_perm(lu[2 * q + 1], lu[2 * q], 0x07060302u);
#else
        H.w[q] = (u[2 * q + 1] & 0xFFFF0000u) | (u[2 * q] >> 16);
        L.w[q] = (lu[2 * q + 1] & 0xFFFF0000u) | (lu[2 * q] >> 16);
#endif
    }
    hi = H.s; lo = L.s;
}

// ---------------- W pre-split: bf16 (layer 1) + fp16 (layers 2,3) ----------------
__global__ __launch_bounds__(256) void wsplit3_kernel(const float* __restrict__ W1,
                                                      const float* __restrict__ W2,
                                                      const float* __restrict__ W3,
                                                      uint4* __restrict__ wh,
                                                      uint4* __restrict__ wl) {
    int b = blockIdx.x;              // 0..23
    int layer = b >> 3;
    const float* W = (layer == 0) ? W1 : (layer == 1) ? W2 : W3;
    int i = (b & 7) * 256 + threadIdx.x;      // 0..2047
    int lane_e = i & 63;
    int ks = (i >> 6) & 3;
    int cf = i >> 8;
    int colb = cf * 16 + (lane_e & 15);
    int rowb = ks * 32 + (lane_e >> 4) * 8;
    float wvv[8];
    #pragma unroll
    for (int j = 0; j < 8; ++j) wvv[j] = W[(rowb + j) * DD + colb];
    if (layer == 0) {
        short8 h, l;
        split8(wvv, h, l);
        union { short8 s; uint4 u; } ch, cl;
        ch.s = h; cl.s = l;
        wh[i] = ch.u;
        wl[i] = cl.u;
    } else {
        half8 h, l;
        split8h(wvv, h, l);
        union { half8 s; uint4 u; } ch, cl;
        ch.s = h; cl.s = l;
        wh[layer * 2048 + i] = ch.u;
        wl[layer * 2048 + i] = cl.u;
    }
}

// ---------------- layer-1 MFMA GEMM (fp32 input, bf16 Markidis, W-prefetch) ----------------
__global__ __launch_bounds__(256) void gemm_norm_kernel(
    const float* __restrict__ X, const uint4* __restrict__ whg,
    const uint4* __restrict__ wlg,
    const float* __restrict__ dinv, __half* __restrict__ G)
{
    const int tid  = threadIdx.x;
    const int base = blockIdx.x * 128;
    const int lane = tid & 63;
    const int wv   = tid >> 6;
    const int kg   = lane >> 4;
    const int mcol = lane & 15;

    const int node0 = base + wv * 32 + mcol;
    const int node1 = node0 + 16;

    short8 xh[2][4], xl[2][4];
    #pragma unroll
    for (int rf = 0; rf < 2; ++rf) {
        int arow = rf ? node1 : node0;
        if (arow >= NN) arow = NN - 1;
        const float* xr = X + (size_t)arow * DD;
        #pragma unroll
        for (int ks = 0; ks < 4; ++ks) {
            int k0 = ks * 32 + kg * 8;
            float av[8];
            *(float4*)&av[0] = *(const float4*)&xr[k0];
            *(float4*)&av[4] = *(const float4*)&xr[k0 + 4];
            split8t(av, xh[rf][ks], xl[rf][ks]);
        }
    }
    const float di0 = dinv[node0 < NN ? node0 : NN - 1];
    const float di1 = dinv[node1 < NN ? node1 : NN - 1];

    uint4 bh[4], bl[4], bhn[4], bln[4];
    #pragma unroll
    for (int ks = 0; ks < 4; ++ks) {
        bh[ks] = whg[ks * 64 + lane];
        bl[ks] = wlg[ks * 64 + lane];
    }

    #pragma unroll 1
    for (int cf = 0; cf < 8; ++cf) {
        if (cf < 7) {
            #pragma unroll
            for (int ks = 0; ks < 4; ++ks) {
                bhn[ks] = whg[((cf + 1) * 4 + ks) * 64 + lane];
                bln[ks] = wlg[((cf + 1) * 4 + ks) * 64 + lane];
            }
        }
        f32x4 acc0 = {0.f, 0.f, 0.f, 0.f};
        f32x4 acc1 = {0.f, 0.f, 0.f, 0.f};
        #pragma unroll
        for (int ks = 0; ks < 4; ++ks) {
            union { uint4 u; short8 s; } ch, cl;
            ch.u = bh[ks];
            cl.u = bl[ks];
            acc0 = __builtin_amdgcn_mfma_f32_16x16x32_bf16(ch.s, xh[0][ks], acc0, 0, 0, 0);
            acc0 = __builtin_amdgcn_mfma_f32_16x16x32_bf16(cl.s, xh[0][ks], acc0, 0, 0, 0);
            acc0 = __builtin_amdgcn_mfma_f32_16x16x32_bf16(ch.s, xl[0][ks], acc0, 0, 0, 0);
            acc1 = __builtin_amdgcn_mfma_f32_16x16x32_bf16(ch.s, xh[1][ks], acc1, 0, 0, 0);
            acc1 = __builtin_amdgcn_mfma_f32_16x16x32_bf16(cl.s, xh[1][ks], acc1, 0, 0, 0);
            acc1 = __builtin_amdgcn_mfma_f32_16x16x32_bf16(ch.s, xl[1][ks], acc1, 0, 0, 0);
        }
        const int fb = cf * 16 + kg * 4;
        if (node0 < NN) {
            __half2 p0 = __floats2half2_rn(acc0[0] * di0, acc0[1] * di0);
            __half2 p1 = __floats2half2_rn(acc0[2] * di0, acc0[3] * di0);
            uint2 st;
            st.x = *reinterpret_cast<unsigned int*>(&p0);
            st.y = *reinterpret_cast<unsigned int*>(&p1);
            *(uint2*)&G[(size_t)node0 * DD + fb] = st;
        }
        if (node1 < NN) {
            __half2 p0 = __floats2half2_rn(acc1[0] * di1, acc1[1] * di1);
            __half2 p1 = __floats2half2_rn(acc1[2] * di1, acc1[3] * di1);
            uint2 st;
            st.x = *reinterpret_cast<unsigned int*>(&p0);
            st.y = *reinterpret_cast<unsigned int*>(&p1);
            *(uint2*)&G[(size_t)node1 * DD + fb] = st;
        }
        #pragma unroll
        for (int ks = 0; ks < 4; ++ks) { bh[ks] = bhn[ks]; bl[ks] = bln[ks]; }
    }
}

// ---------------- layers 2-3 MFMA GEMM (fp16 input fed EXACTLY, f16 MFMA) ----------------
__global__ __launch_bounds__(256) void gemm_f16_kernel(
    const __half* __restrict__ X, const uint4* __restrict__ whg,
    const uint4* __restrict__ wlg,
    const float* __restrict__ dinv, __half* __restrict__ G)
{
    const int tid  = threadIdx.x;
    const int base = blockIdx.x * 128;
    const int lane = tid & 63;
    const int wv   = tid >> 6;
    const int kg   = lane >> 4;
    const int mcol = lane & 15;

    const int node0 = base + wv * 32 + mcol;
    const int node1 = node0 + 16;

    uint4 xb[2][4];
    #pragma unroll
    for (int rf = 0; rf < 2; ++rf) {
        int arow = rf ? node1 : node0;
        if (arow >= NN) arow = NN - 1;
        const __half* xr = X + (size_t)arow * DD;
        #pragma unroll
        for (int ks = 0; ks < 4; ++ks)
            xb[rf][ks] = *(const uint4*)&xr[ks * 32 + kg * 8];
    }
    const float di0 = dinv[node0 < NN ? node0 : NN - 1];
    const float di1 = dinv[node1 < NN ? node1 : NN - 1];

    uint4 ah[4], al[4], ahn[4], aln[4];
    #pragma unroll
    for (int ks = 0; ks < 4; ++ks) {
        ah[ks] = whg[ks * 64 + lane];
        al[ks] = wlg[ks * 64 + lane];
    }

    #pragma unroll 1
    for (int cf = 0; cf < 8; ++cf) {
        if (cf < 7) {
            #pragma unroll
            for (int ks = 0; ks < 4; ++ks) {
                ahn[ks] = whg[((cf + 1) * 4 + ks) * 64 + lane];
                aln[ks] = wlg[((cf + 1) * 4 + ks) * 64 + lane];
            }
        }
        f32x4 acc0 = {0.f, 0.f, 0.f, 0.f};
        f32x4 acc1 = {0.f, 0.f, 0.f, 0.f};
        #pragma unroll
        for (int ks = 0; ks < 4; ++ks) {
            union { uint4 u; half8 h; } wh_, wl_, x0, x1;
            wh_.u = ah[ks]; wl_.u = al[ks];
            x0.u = xb[0][ks]; x1.u = xb[1][ks];
            acc0 = __builtin_amdgcn_mfma_f32_16x16x32_f16(wh_.h, x0.h, acc0, 0, 0, 0);
            acc0 = __builtin_amdgcn_mfma_f32_16x16x32_f16(wl_.h, x0.h, acc0, 0, 0, 0);
            acc1 = __builtin_amdgcn_mfma_f32_16x16x32_f16(wh_.h, x1.h, acc1, 0, 0, 0);
            acc1 = __builtin_amdgcn_mfma_f32_16x16x32_f16(wl_.h, x1.h, acc1, 0, 0, 0);
        }
        const int fb = cf * 16 + kg * 4;
        if (node0 < NN) {
            __half2 p0 = __floats2half2_rn(acc0[0] * di0, acc0[1] * di0);
            __half2 p1 = __floats2half2_rn(acc0[2] * di0, acc0[3] * di0);
            uint2 st;
            st.x = *reinterpret_cast<unsigned int*>(&p0);
            st.y = *reinterpret_cast<unsigned int*>(&p1);
            *(uint2*)&G[(size_t)node0 * DD + fb] = st;
        }
        if (node1 < NN) {
            __half2 p0 = __floats2half2_rn(acc1[0] * di1, acc1[1] * di1);
            __half2 p1 = __floats2half2_rn(acc1[2] * di1, acc1[3] * di1);
            uint2 st;
            st.x = *reinterpret_cast<unsigned int*>(&p0);
            st.y = *reinterpret_cast<unsigned int*>(&p1);
            *(uint2*)&G[(size_t)node1 * DD + fb] = st;
        }
        #pragma unroll
        for (int ks = 0; ks < 4; ++ks) { ah[ks] = ahn[ks]; al[ks] = aln[ks]; }
    }
}

// ---------------- gather helpers ----------------
__device__ __forceinline__ float4 gload(const __half* __restrict__ g, int idx, int cq) {
    uint2 u = *(const uint2*)(g + (size_t)idx * DD + cq * 4);
    __half2 h0 = *reinterpret_cast<const __half2*>(&u.x);
    __half2 h1 = *reinterpret_cast<const __half2*>(&u.y);
    float2 f0 = __half22float2(h0);
    float2 f1 = __half22float2(h1);
    return make_float4(f0.x, f0.y, f1.x, f1.y);
}

__device__ __forceinline__ float4 gather_row(const __half* __restrict__ g,
                                             const int* __restrict__ off,
                                             const int* __restrict__ csr,
                                             const float* __restrict__ dinv,
                                             const float4 bb, int node,
                                             int sub, int cq) {
    float4 acc = make_float4(0.f, 0.f, 0.f, 0.f);
    float4 acc2 = make_float4(0.f, 0.f, 0.f, 0.f);
    if (sub == 0) acc = gload(g, node, cq);       // self-loop

    const int e0 = off[node], end = off[node + 1];
    const int cnt = end - e0;
    const int pairs = cnt >> 1;
    const int np4 = pairs & ~3;

    if (np4) {
        int i0 = csr[e0 + 0 + sub];
        int i1 = csr[e0 + 2 + sub];
        int i2 = csr[e0 + 4 + sub];
        int i3 = csr[e0 + 6 + sub];
        for (int p = 4; p < np4; p += 4) {
            int b0 = e0 + 2 * p + sub;
            int j0 = csr[b0];
            int j1 = csr[b0 + 2];
            int j2 = csr[b0 + 4];
            int j3 = csr[b0 + 6];
            float4 v0 = gload(g, i0, cq);
            float4 v1 = gload(g, i1, cq);
            float4 v2 = gload(g, i2, cq);
            float4 v3 = gload(g, i3, cq);
            acc.x += v0.x + v2.x; acc.y += v0.y + v2.y;
            acc.z += v0.z + v2.z; acc.w += v0.w + v2.w;
            acc2.x += v1.x + v3.x; acc2.y += v1.y + v3.y;
            acc2.z += v1.z + v3.z; acc2.w += v1.w + v3.w;
            i0 = j0; i1 = j1; i2 = j2; i3 = j3;
        }
        float4 v0 = gload(g, i0, cq);
        float4 v1 = gload(g, i1, cq);
        float4 v2 = gload(g, i2, cq);
        float4 v3 = gload(g, i3, cq);
        acc.x += v0.x + v2.x; acc.y += v0.y + v2.y;
        acc.z += v0.z + v2.z; acc.w += v0.w + v2.w;
        acc2.x += v1.x + v3.x; acc2.y += v1.y + v3.y;
        acc2.z += v1.z + v3.z; acc2.w += v1.w + v3.w;
    }
    for (int q = np4; q < pairs; ++q) {
        int s = csr[e0 + 2 * q + sub];
        float4 v = gload(g, s, cq);
        acc.x += v.x; acc.y += v.y; acc.z += v.z; acc.w += v.w;
    }
    if ((cnt & 1) && sub == 0) {
        int s = csr[end - 1];
        float4 v = gload(g, s, cq);
        acc.x += v.x; acc.y += v.y; acc.z += v.z; acc.w += v.w;
    }

    acc.x += acc2.x; acc.y += acc2.y; acc.z += acc2.z; acc.w += acc2.w;
    acc.x += __shfl_xor(acc.x, 32, 64);
    acc.y += __shfl_xor(acc.y, 32, 64);
    acc.z += __shfl_xor(acc.z, 32, 64);
    acc.w += __shfl_xor(acc.w, 32, 64);

    float di = dinv[node];
    float4 o;
    o.x = fmaxf(fmaf(acc.x, di, bb.x), 0.f);
    o.y = fmaxf(fmaf(acc.y, di, bb.y), 0.f);
    o.z = fmaxf(fmaf(acc.z, di, bb.z), 0.f);
    o.w = fmaxf(fmaf(acc.w, di, bb.w), 0.f);
    return o;
}

// ---------------- gather-aggregate + bias + relu ----------------
template <typename OutT>
__global__ __launch_bounds__(256) void agg_kernel(
    const __half* __restrict__ g, const float* __restrict__ dinv,
    const int* __restrict__ off, const int* __restrict__ csr,
    const float* __restrict__ bias, OutT* __restrict__ out)
{
    const int wid  = threadIdx.x >> 6;
    const int lane = threadIdx.x & 63;
    const int sub  = lane >> 5;
    const int cq   = lane & 31;
    const float4 bb = ((const float4*)bias)[cq];
    const int ngroups = (NN + 3) / 4;

    for (int grp = blockIdx.x; grp < ngroups; grp += AGG_BLOCKS) {
        int node = grp * 4 + wid;
        if (node >= NN) continue;
        float4 o = gather_row(g, off, csr, dinv, bb, node, sub, cq);
        if (sub == 0) {
            if constexpr (sizeof(OutT) == 4) {
                ((float4*)out)[(size_t)node * 32 + cq] = o;
            } else {
                uint2 st;
                __half2 h0 = __floats2half2_rn(o.x, o.y);
                __half2 h1 = __floats2half2_rn(o.z, o.w);
                st.x = *reinterpret_cast<unsigned int*>(&h0);
                st.y = *reinterpret_cast<unsigned int*>(&h1);
                *(uint2*)((__half*)out + (size_t)node * DD + cq * 4) = st;
            }
        }
    }
}

extern "C" void kernel_launch(void* const* d_in, const int* in_sizes, int n_in,
                              void* d_out, int out_size, void* d_ws, size_t ws_size,
                              hipStream_t stream)
{
    const float* x  = (const float*)d_in[0];
    const float* W1 = (const float*)d_in[1];
    const float* b1 = (const float*)d_in[2];
    const float* W2 = (const float*)d_in[3];
    const float* b2 = (const float*)d_in[4];
    const float* W3 = (const float*)d_in[5];
    const float* b3 = (const float*)d_in[6];
    const int*   ei = (const int*)d_in[7];

    const int E = in_sizes[7] / 2;          // 1,600,000
    const int* src = ei;
    const int* dst = ei + E;

    float* out = (float*)d_out;

    // ---- workspace layout ----
    char* wsb = (char*)d_ws;
    size_t p = 0;
    int* offsets  = (int*)(wsb + p); p += ((size_t)(NN + 1) * 4 + 1023) & ~1023ull;
    int* csr      = (int*)(wsb + p); p += ((size_t)E * 4 + 1023) & ~1023ull;
    float* dinv   = (float*)(wsb + p); p += ((size_t)NN * 4 + 1023) & ~1023ull;
    int* cursor   = (int*)(wsb + p); p += ((size_t)NN * 4 + 1023) & ~1023ull;
    int* cur      = (int*)(wsb + p); p += (size_t)NBUCK * CURPAD * 4;
    uint4* wh     = (uint4*)(wsb + p); p += 3 * 2048 * sizeof(uint4);
    uint4* wl     = (uint4*)(wsb + p); p += 3 * 2048 * sizeof(uint4);
    int* packed   = (int*)(wsb + p); p += ((size_t)NBUCK * CAP * 4 + 1023) & ~1023ull;
    __half* g     = (__half*)(wsb + p); p += (size_t)NN * DD * 2;
    __half* g2    = (__half*)(wsb + p); p += (size_t)NN * DD * 2;

    // ---- CSR build (parallel bucket counting-sort) + W pre-split ----
    hipMemsetAsync(cur, 0, (size_t)NBUCK * CURPAD * 4, stream);
    bucket_scatter_kernel<<<APASS, 256, 0, stream>>>(src, dst, E, cur, packed);
    bucket_count_kernel<<<NBUCK, 256, 0, stream>>>(cur, packed, offsets, cursor, dinv);
    bucket_fill_kernel<<<FILLB, 256, 0, stream>>>(cur, packed, cursor, csr);
    wsplit3_kernel<<<24, 256, 0, stream>>>(W1, W2, W3, wh, wl);

    const int gemm_grid = (NN + 127) / 128;               // 782

    // ---- layer 1 ----
    gemm_norm_kernel<<<gemm_grid, 256, 0, stream>>>(x, wh, wl, dinv, g);
    agg_kernel<__half><<<AGG_BLOCKS, 256, 0, stream>>>(g, dinv, offsets, csr, b1, g2);
    // ---- layer 2 ----
    gemm_f16_kernel<<<gemm_grid, 256, 0, stream>>>(g2, wh + 2048, wl + 2048, dinv, g);
    agg_kernel<__half><<<AGG_BLOCKS, 256, 0, stream>>>(g, dinv, offsets, csr, b2, g2);
    // ---- layer 3 ----
    gemm_f16_kernel<<<gemm_grid, 256, 0, stream>>>(g2, wh + 4096, wl + 4096, dinv, g);
    agg_kernel<float><<<AGG_BLOCKS, 256, 0, stream>>>(g, dinv, offsets, csr, b3, out);
}

// Round 17
// 358.350 us; speedup vs baseline: 1.0231x; 1.0231x over previous
//
#include <hip/hip_runtime.h>
#include <hip/hip_fp16.h>
#include <math.h>

#define NN 100000
#define DD 128
#define AGG_BLOCKS 2048

#define NBUCK 98          // ceil(NN / 1024)
#define BSH 10            // bucket width 1024 nodes
#define BW 1024
#define CAP 18432         // per-bucket edge capacity (mean 16384, sigma ~127)
#define APASS 196         // bucket_scatter blocks
#define CURPAD 32         // ints between cursors (one 128B line each)

typedef short short8 __attribute__((ext_vector_type(8)));
typedef _Float16 half8 __attribute__((ext_vector_type(8)));
typedef float f32x4 __attribute__((ext_vector_type(4)));

// ---------------- bucket pass A: count + scatter packed edges ----------------
__global__ __launch_bounds__(256) void bucket_scatter_kernel(
    const int* __restrict__ src, const int* __restrict__ dst, int E,
    int* __restrict__ cur, int* __restrict__ packed)
{
    __shared__ int h[NBUCK];
    __shared__ int base[NBUCK];
    __shared__ int c2[NBUCK];

    const int tid = threadIdx.x;
    const int chunk = (E + APASS - 1) / APASS;
    const int e0 = blockIdx.x * chunk;
    const int e1 = min(e0 + chunk, E);

    if (tid < NBUCK) { h[tid] = 0; c2[tid] = 0; }
    __syncthreads();

    for (int e = e0 + tid; e < e1; e += 256)
        atomicAdd(&h[dst[e] >> BSH], 1);
    __syncthreads();

    if (tid < NBUCK && h[tid] > 0)
        base[tid] = atomicAdd(&cur[tid * CURPAD], h[tid]);
    __syncthreads();

    for (int e = e0 + tid; e < e1; e += 256) {
        int d = dst[e];
        int b = d >> BSH;
        int r = atomicAdd(&c2[b], 1);
        int pos = base[b] + r;
        if (pos < CAP)
            packed[b * CAP + pos] = ((d & (BW - 1)) << 17) | src[e];
    }
}

// ---------------- bucket pass B: scan 98 bucket counts ----------------
__global__ void bucket_scan_kernel(const int* __restrict__ cur,
                                   int* __restrict__ cbase,
                                   int* __restrict__ offsets) {
    if (threadIdx.x == 0) {
        int run = 0;
        for (int b = 0; b < NBUCK; ++b) {
            int c = cur[b * CURPAD];
            if (c > CAP) c = CAP;
            cbase[b] = run;
            run += c;
        }
        offsets[NN] = run;
    }
}

// ---------------- bucket pass C: per-bucket CSR + offsets + dinv ----------------
__global__ __launch_bounds__(256) void bucket_csr_kernel(
    const int* __restrict__ cur, const int* __restrict__ cbase,
    const int* __restrict__ packed,
    int* __restrict__ offsets, float* __restrict__ dinv,
    int* __restrict__ csr)
{
    __shared__ int cnt[BW];
    __shared__ int excl[BW];
    __shared__ int ts[256];

    const int tid = threadIdx.x;
    const int b = blockIdx.x;
    int c = cur[b * CURPAD];
    if (c > CAP) c = CAP;
    const int cb = cbase[b];
    const int pbase = b * CAP;

    #pragma unroll
    for (int k = 0; k < 4; ++k) cnt[tid * 4 + k] = 0;
    __syncthreads();

    for (int i = tid; i < c; i += 256)
        atomicAdd(&cnt[packed[pbase + i] >> 17], 1);
    __syncthreads();

    int v[4];
    int s = 0;
    #pragma unroll
    for (int k = 0; k < 4; ++k) { v[k] = cnt[tid * 4 + k]; s += v[k]; }
    ts[tid] = s;
    __syncthreads();
    for (int d = 1; d < 256; d <<= 1) {
        int t = (tid >= d) ? ts[tid - d] : 0;
        __syncthreads();
        ts[tid] += t;
        __syncthreads();
    }
    int ex = ts[tid] - s;

    int run = 0;
    #pragma unroll
    for (int k = 0; k < 4; ++k) {
        int dl = tid * 4 + k;
        excl[dl] = ex + run;
        int node = b * BW + dl;
        if (node < NN) {
            offsets[node] = cb + ex + run;
            dinv[node] = rsqrtf((float)v[k] + 1.0f);
        }
        run += v[k];
    }
    __syncthreads();

    for (int i = tid; i < c; i += 256) {
        int p = packed[pbase + i];
        int dl = p >> 17;
        int r = atomicAdd(&excl[dl], 1);
        csr[cb + r] = p & 0x1FFFF;
    }
}

// ---------------- helpers: fp32 -> bf16 / fp16 splits ----------------
__device__ __forceinline__ unsigned short f2bf(float f) {
    unsigned int u = __float_as_uint(f);
    unsigned int r = u + 0x7FFFu + ((u >> 16) & 1u);
    return (unsigned short)(r >> 16);
}

__device__ __forceinline__ void split8(const float* v, short8& hi, short8& lo) {
    #pragma unroll
    for (int j = 0; j < 8; ++j) {
        float f = v[j];
        unsigned short h = f2bf(f);
        float fl = f - __uint_as_float(((unsigned int)h) << 16);
        hi[j] = (short)h;
        lo[j] = (short)f2bf(fl);
    }
}

// fp16 2-term split: W = hi + lo with fp32-compensated residual
__device__ __forceinline__ void split8h(const float* v, half8& hi, half8& lo) {
    #pragma unroll
    for (int j = 0; j < 8; ++j) {
        _Float16 h = (_Float16)v[j];
        float fl = v[j] - (float)h;
        hi[j] = h;
        lo[j] = (_Float16)fl;
    }
}

// truncating bf16 split (exactly compensated); packs via v_perm.
__device__ __forceinline__ void split8t(const float* v, short8& hi, short8& lo) {
    const unsigned int* u = (const unsigned int*)v;
    float lof[8];
    #pragma unroll
    for (int j = 0; j < 8; ++j)
        lof[j] = v[j] - __uint_as_float(u[j] & 0xFFFF0000u);
    const unsigned int* lu = (const unsigned int*)lof;
    union { short8 s; unsigned int w[4]; } H, L;
    #pragma unroll
    for (int q = 0; q < 4; ++q) {
#if __has_builtin(__builtin_amdgcn_perm)
        H.w[q] = __builtin_amdgcn_perm(u[2 * q + 1], u[2 * q], 0x07060302u);
        L.w[q] = __builtin_amdgcn_perm(lu[2 * q + 1], lu[2 * q], 0x07060302u);
#else
        H.w[q] = (u[2 * q + 1] & 0xFFFF0000u) | (u[2 * q] >> 16);
        L.w[q] = (lu[2 * q + 1] & 0xFFFF0000u) | (lu[2 * q] >> 16);
#endif
    }
    hi = H.s; lo = L.s;
}

// ---------------- W pre-split: bf16 (layer 1) + fp16 (layers 2,3) ----------------
__global__ __launch_bounds__(256) void wsplit3_kernel(const float* __restrict__ W1,
                                                      const float* __restrict__ W2,
                                                      const float* __restrict__ W3,
                                                      uint4* __restrict__ wh,
                                                      uint4* __restrict__ wl) {
    int b = blockIdx.x;              // 0..23
    int layer = b >> 3;
    const float* W = (layer == 0) ? W1 : (layer == 1) ? W2 : W3;
    int i = (b & 7) * 256 + threadIdx.x;      // 0..2047
    int lane_e = i & 63;
    int ks = (i >> 6) & 3;
    int cf = i >> 8;
    int colb = cf * 16 + (lane_e & 15);
    int rowb = ks * 32 + (lane_e >> 4) * 8;
    float wvv[8];
    #pragma unroll
    for (int j = 0; j < 8; ++j) wvv[j] = W[(rowb + j) * DD + colb];
    if (layer == 0) {
        short8 h, l;
        split8(wvv, h, l);
        union { short8 s; uint4 u; } ch, cl;
        ch.s = h; cl.s = l;
        wh[i] = ch.u;
        wl[i] = cl.u;
    } else {
        half8 h, l;
        split8h(wvv, h, l);
        union { half8 s; uint4 u; } ch, cl;
        ch.s = h; cl.s = l;
        wh[layer * 2048 + i] = ch.u;
        wl[layer * 2048 + i] = cl.u;
    }
}

// ---------------- layer-1 MFMA GEMM (fp32 input, bf16 Markidis, W-prefetch) ----------------
__global__ __launch_bounds__(256) void gemm_norm_kernel(
    const float* __restrict__ X, const uint4* __restrict__ whg,
    const uint4* __restrict__ wlg,
    const float* __restrict__ dinv, __half* __restrict__ G)
{
    const int tid  = threadIdx.x;
    const int base = blockIdx.x * 128;
    const int lane = tid & 63;
    const int wv   = tid >> 6;
    const int kg   = lane >> 4;
    const int mcol = lane & 15;

    const int node0 = base + wv * 32 + mcol;
    const int node1 = node0 + 16;

    short8 xh[2][4], xl[2][4];
    #pragma unroll
    for (int rf = 0; rf < 2; ++rf) {
        int arow = rf ? node1 : node0;
        if (arow >= NN) arow = NN - 1;
        const float* xr = X + (size_t)arow * DD;
        #pragma unroll
        for (int ks = 0; ks < 4; ++ks) {
            int k0 = ks * 32 + kg * 8;
            float av[8];
            *(float4*)&av[0] = *(const float4*)&xr[k0];
            *(float4*)&av[4] = *(const float4*)&xr[k0 + 4];
            split8t(av, xh[rf][ks], xl[rf][ks]);
        }
    }
    const float di0 = dinv[node0 < NN ? node0 : NN - 1];
    const float di1 = dinv[node1 < NN ? node1 : NN - 1];

    uint4 bh[4], bl[4], bhn[4], bln[4];
    #pragma unroll
    for (int ks = 0; ks < 4; ++ks) {
        bh[ks] = whg[ks * 64 + lane];
        bl[ks] = wlg[ks * 64 + lane];
    }

    #pragma unroll 1
    for (int cf = 0; cf < 8; ++cf) {
        if (cf < 7) {
            #pragma unroll
            for (int ks = 0; ks < 4; ++ks) {
                bhn[ks] = whg[((cf + 1) * 4 + ks) * 64 + lane];
                bln[ks] = wlg[((cf + 1) * 4 + ks) * 64 + lane];
            }
        }
        f32x4 acc0 = {0.f, 0.f, 0.f, 0.f};
        f32x4 acc1 = {0.f, 0.f, 0.f, 0.f};
        #pragma unroll
        for (int ks = 0; ks < 4; ++ks) {
            union { uint4 u; short8 s; } ch, cl;
            ch.u = bh[ks];
            cl.u = bl[ks];
            acc0 = __builtin_amdgcn_mfma_f32_16x16x32_bf16(ch.s, xh[0][ks], acc0, 0, 0, 0);
            acc0 = __builtin_amdgcn_mfma_f32_16x16x32_bf16(cl.s, xh[0][ks], acc0, 0, 0, 0);
            acc0 = __builtin_amdgcn_mfma_f32_16x16x32_bf16(ch.s, xl[0][ks], acc0, 0, 0, 0);
            acc1 = __builtin_amdgcn_mfma_f32_16x16x32_bf16(ch.s, xh[1][ks], acc1, 0, 0, 0);
            acc1 = __builtin_amdgcn_mfma_f32_16x16x32_bf16(cl.s, xh[1][ks], acc1, 0, 0, 0);
            acc1 = __builtin_amdgcn_mfma_f32_16x16x32_bf16(ch.s, xl[1][ks], acc1, 0, 0, 0);
        }
        const int fb = cf * 16 + kg * 4;
        if (node0 < NN) {
            __half2 p0 = __floats2half2_rn(acc0[0] * di0, acc0[1] * di0);
            __half2 p1 = __floats2half2_rn(acc0[2] * di0, acc0[3] * di0);
            uint2 st;
            st.x = *reinterpret_cast<unsigned int*>(&p0);
            st.y = *reinterpret_cast<unsigned int*>(&p1);
            *(uint2*)&G[(size_t)node0 * DD + fb] = st;
        }
        if (node1 < NN) {
            __half2 p0 = __floats2half2_rn(acc1[0] * di1, acc1[1] * di1);
            __half2 p1 = __floats2half2_rn(acc1[2] * di1, acc1[3] * di1);
            uint2 st;
            st.x = *reinterpret_cast<unsigned int*>(&p0);
            st.y = *reinterpret_cast<unsigned int*>(&p1);
            *(uint2*)&G[(size_t)node1 * DD + fb] = st;
        }
        #pragma unroll
        for (int ks = 0; ks < 4; ++ks) { bh[ks] = bhn[ks]; bl[ks] = bln[ks]; }
    }
}

// ---------------- layers 2-3 MFMA GEMM (fp16 input fed EXACTLY, f16 MFMA) ----------------
__global__ __launch_bounds__(256) void gemm_f16_kernel(
    const __half* __restrict__ X, const uint4* __restrict__ whg,
    const uint4* __restrict__ wlg,
    const float* __restrict__ dinv, __half* __restrict__ G)
{
    const int tid  = threadIdx.x;
    const int base = blockIdx.x * 128;
    const int lane = tid & 63;
    const int wv   = tid >> 6;
    const int kg   = lane >> 4;
    const int mcol = lane & 15;

    const int node0 = base + wv * 32 + mcol;
    const int node1 = node0 + 16;

    uint4 xb[2][4];
    #pragma unroll
    for (int rf = 0; rf < 2; ++rf) {
        int arow = rf ? node1 : node0;
        if (arow >= NN) arow = NN - 1;
        const __half* xr = X + (size_t)arow * DD;
        #pragma unroll
        for (int ks = 0; ks < 4; ++ks)
            xb[rf][ks] = *(const uint4*)&xr[ks * 32 + kg * 8];
    }
    const float di0 = dinv[node0 < NN ? node0 : NN - 1];
    const float di1 = dinv[node1 < NN ? node1 : NN - 1];

    uint4 ah[4], al[4], ahn[4], aln[4];
    #pragma unroll
    for (int ks = 0; ks < 4; ++ks) {
        ah[ks] = whg[ks * 64 + lane];
        al[ks] = wlg[ks * 64 + lane];
    }

    #pragma unroll 1
    for (int cf = 0; cf < 8; ++cf) {
        if (cf < 7) {
            #pragma unroll
            for (int ks = 0; ks < 4; ++ks) {
                ahn[ks] = whg[((cf + 1) * 4 + ks) * 64 + lane];
                aln[ks] = wlg[((cf + 1) * 4 + ks) * 64 + lane];
            }
        }
        f32x4 acc0 = {0.f, 0.f, 0.f, 0.f};
        f32x4 acc1 = {0.f, 0.f, 0.f, 0.f};
        #pragma unroll
        for (int ks = 0; ks < 4; ++ks) {
            union { uint4 u; half8 h; } wh_, wl_, x0, x1;
            wh_.u = ah[ks]; wl_.u = al[ks];
            x0.u = xb[0][ks]; x1.u = xb[1][ks];
            acc0 = __builtin_amdgcn_mfma_f32_16x16x32_f16(wh_.h, x0.h, acc0, 0, 0, 0);
            acc0 = __builtin_amdgcn_mfma_f32_16x16x32_f16(wl_.h, x0.h, acc0, 0, 0, 0);
            acc1 = __builtin_amdgcn_mfma_f32_16x16x32_f16(wh_.h, x1.h, acc1, 0, 0, 0);
            acc1 = __builtin_amdgcn_mfma_f32_16x16x32_f16(wl_.h, x1.h, acc1, 0, 0, 0);
        }
        const int fb = cf * 16 + kg * 4;
        if (node0 < NN) {
            __half2 p0 = __floats2half2_rn(acc0[0] * di0, acc0[1] * di0);
            __half2 p1 = __floats2half2_rn(acc0[2] * di0, acc0[3] * di0);
            uint2 st;
            st.x = *reinterpret_cast<unsigned int*>(&p0);
            st.y = *reinterpret_cast<unsigned int*>(&p1);
            *(uint2*)&G[(size_t)node0 * DD + fb] = st;
        }
        if (node1 < NN) {
            __half2 p0 = __floats2half2_rn(acc1[0] * di1, acc1[1] * di1);
            __half2 p1 = __floats2half2_rn(acc1[2] * di1, acc1[3] * di1);
            uint2 st;
            st.x = *reinterpret_cast<unsigned int*>(&p0);
            st.y = *reinterpret_cast<unsigned int*>(&p1);
            *(uint2*)&G[(size_t)node1 * DD + fb] = st;
        }
        #pragma unroll
        for (int ks = 0; ks < 4; ++ks) { ah[ks] = ahn[ks]; al[ks] = aln[ks]; }
    }
}

// ---------------- gather helpers ----------------
__device__ __forceinline__ float4 gload(const __half* __restrict__ g, int idx, int cq) {
    uint2 u = *(const uint2*)(g + (size_t)idx * DD + cq * 4);
    __half2 h0 = *reinterpret_cast<const __half2*>(&u.x);
    __half2 h1 = *reinterpret_cast<const __half2*>(&u.y);
    float2 f0 = __half22float2(h0);
    float2 f1 = __half22float2(h1);
    return make_float4(f0.x, f0.y, f1.x, f1.y);
}

__device__ __forceinline__ float4 gather_row(const __half* __restrict__ g,
                                             const int* __restrict__ off,
                                             const int* __restrict__ csr,
                                             const float* __restrict__ dinv,
                                             const float4 bb, int node,
                                             int sub, int cq) {
    float4 acc = make_float4(0.f, 0.f, 0.f, 0.f);
    float4 acc2 = make_float4(0.f, 0.f, 0.f, 0.f);
    if (sub == 0) acc = gload(g, node, cq);       // self-loop

    const int e0 = off[node], end = off[node + 1];
    const int cnt = end - e0;
    const int pairs = cnt >> 1;
    const int np4 = pairs & ~3;

    if (np4) {
        int i0 = csr[e0 + 0 + sub];
        int i1 = csr[e0 + 2 + sub];
        int i2 = csr[e0 + 4 + sub];
        int i3 = csr[e0 + 6 + sub];
        for (int p = 4; p < np4; p += 4) {
            int b0 = e0 + 2 * p + sub;
            int j0 = csr[b0];
            int j1 = csr[b0 + 2];
            int j2 = csr[b0 + 4];
            int j3 = csr[b0 + 6];
            float4 v0 = gload(g, i0, cq);
            float4 v1 = gload(g, i1, cq);
            float4 v2 = gload(g, i2, cq);
            float4 v3 = gload(g, i3, cq);
            acc.x += v0.x + v2.x; acc.y += v0.y + v2.y;
            acc.z += v0.z + v2.z; acc.w += v0.w + v2.w;
            acc2.x += v1.x + v3.x; acc2.y += v1.y + v3.y;
            acc2.z += v1.z + v3.z; acc2.w += v1.w + v3.w;
            i0 = j0; i1 = j1; i2 = j2; i3 = j3;
        }
        float4 v0 = gload(g, i0, cq);
        float4 v1 = gload(g, i1, cq);
        float4 v2 = gload(g, i2, cq);
        float4 v3 = gload(g, i3, cq);
        acc.x += v0.x + v2.x; acc.y += v0.y + v2.y;
        acc.z += v0.z + v2.z; acc.w += v0.w + v2.w;
        acc2.x += v1.x + v3.x; acc2.y += v1.y + v3.y;
        acc2.z += v1.z + v3.z; acc2.w += v1.w + v3.w;
    }
    for (int q = np4; q < pairs; ++q) {
        int s = csr[e0 + 2 * q + sub];
        float4 v = gload(g, s, cq);
        acc.x += v.x; acc.y += v.y; acc.z += v.z; acc.w += v.w;
    }
    if ((cnt & 1) && sub == 0) {
        int s = csr[end - 1];
        float4 v = gload(g, s, cq);
        acc.x += v.x; acc.y += v.y; acc.z += v.z; acc.w += v.w;
    }

    acc.x += acc2.x; acc.y += acc2.y; acc.z += acc2.z; acc.w += acc2.w;
    acc.x += __shfl_xor(acc.x, 32, 64);
    acc.y += __shfl_xor(acc.y, 32, 64);
    acc.z += __shfl_xor(acc.z, 32, 64);
    acc.w += __shfl_xor(acc.w, 32, 64);

    float di = dinv[node];
    float4 o;
    o.x = fmaxf(fmaf(acc.x, di, bb.x), 0.f);
    o.y = fmaxf(fmaf(acc.y, di, bb.y), 0.f);
    o.z = fmaxf(fmaf(acc.z, di, bb.z), 0.f);
    o.w = fmaxf(fmaf(acc.w, di, bb.w), 0.f);
    return o;
}

// ---------------- gather-aggregate + bias + relu ----------------
template <typename OutT>
__global__ __launch_bounds__(256) void agg_kernel(
    const __half* __restrict__ g, const float* __restrict__ dinv,
    const int* __restrict__ off, const int* __restrict__ csr,
    const float* __restrict__ bias, OutT* __restrict__ out)
{
    const int wid  = threadIdx.x >> 6;
    const int lane = threadIdx.x & 63;
    const int sub  = lane >> 5;
    const int cq   = lane & 31;
    const float4 bb = ((const float4*)bias)[cq];
    const int ngroups = (NN + 3) / 4;

    for (int grp = blockIdx.x; grp < ngroups; grp += AGG_BLOCKS) {
        int node = grp * 4 + wid;
        if (node >= NN) continue;
        float4 o = gather_row(g, off, csr, dinv, bb, node, sub, cq);
        if (sub == 0) {
            if constexpr (sizeof(OutT) == 4) {
                ((float4*)out)[(size_t)node * 32 + cq] = o;
            } else {
                uint2 st;
                __half2 h0 = __floats2half2_rn(o.x, o.y);
                __half2 h1 = __floats2half2_rn(o.z, o.w);
                st.x = *reinterpret_cast<unsigned int*>(&h0);
                st.y = *reinterpret_cast<unsigned int*>(&h1);
                *(uint2*)((__half*)out + (size_t)node * DD + cq * 4) = st;
            }
        }
    }
}

extern "C" void kernel_launch(void* const* d_in, const int* in_sizes, int n_in,
                              void* d_out, int out_size, void* d_ws, size_t ws_size,
                              hipStream_t stream)
{
    const float* x  = (const float*)d_in[0];
    const float* W1 = (const float*)d_in[1];
    const float* b1 = (const float*)d_in[2];
    const float* W2 = (const float*)d_in[3];
    const float* b2 = (const float*)d_in[4];
    const float* W3 = (const float*)d_in[5];
    const float* b3 = (const float*)d_in[6];
    const int*   ei = (const int*)d_in[7];

    const int E = in_sizes[7] / 2;          // 1,600,000
    const int* src = ei;
    const int* dst = ei + E;

    float* out = (float*)d_out;

    // ---- workspace layout ----
    char* wsb = (char*)d_ws;
    size_t p = 0;
    int* offsets  = (int*)(wsb + p); p += ((size_t)(NN + 1) * 4 + 1023) & ~1023ull;
    int* csr      = (int*)(wsb + p); p += ((size_t)E * 4 + 1023) & ~1023ull;
    float* dinv   = (float*)(wsb + p); p += ((size_t)NN * 4 + 1023) & ~1023ull;
    int* cur      = (int*)(wsb + p); p += (size_t)NBUCK * CURPAD * 4;
    int* cbase    = (int*)(wsb + p); p += 1024;
    uint4* wh     = (uint4*)(wsb + p); p += 3 * 2048 * sizeof(uint4);
    uint4* wl     = (uint4*)(wsb + p); p += 3 * 2048 * sizeof(uint4);
    int* packed   = (int*)(wsb + p); p += ((size_t)NBUCK * CAP * 4 + 1023) & ~1023ull;
    __half* g     = (__half*)(wsb + p); p += (size_t)NN * DD * 2;
    __half* g2    = (__half*)(wsb + p); p += (size_t)NN * DD * 2;

    // ---- CSR build (bucket counting-sort) + W pre-split ----
    hipMemsetAsync(cur, 0, (size_t)NBUCK * CURPAD * 4, stream);
    bucket_scatter_kernel<<<APASS, 256, 0, stream>>>(src, dst, E, cur, packed);
    bucket_scan_kernel<<<1, 64, 0, stream>>>(cur, cbase, offsets);
    bucket_csr_kernel<<<NBUCK, 256, 0, stream>>>(cur, cbase, packed, offsets, dinv, csr);
    wsplit3_kernel<<<24, 256, 0, stream>>>(W1, W2, W3, wh, wl);

    const int gemm_grid = (NN + 127) / 128;               // 782

    // ---- layer 1 ----
    gemm_norm_kernel<<<gemm_grid, 256, 0, stream>>>(x, wh, wl, dinv, g);
    agg_kernel<__half><<<AGG_BLOCKS, 256, 0, stream>>>(g, dinv, offsets, csr, b1, g2);
    // ---- layer 2 ----
    gemm_f16_kernel<<<gemm_grid, 256, 0, stream>>>(g2, wh + 2048, wl + 2048, dinv, g);
    agg_kernel<__half><<<AGG_BLOCKS, 256, 0, stream>>>(g, dinv, offsets, csr, b2, g2);
    // ---- layer 3 ----
    gemm_f16_kernel<<<gemm_grid, 256, 0, stream>>>(g2, wh + 4096, wl + 4096, dinv, g);
    agg_kernel<float><<<AGG_BLOCKS, 256, 0, stream>>>(g, dinv, offsets, csr, b3, out);
}